// Round 2
// baseline (237.036 us; speedup 1.0000x reference)
//
#include <hip/hip_runtime.h>

// KAN-PINN forward, MI355X.
// Strategy: lanes = collocation points (weights wave-uniform -> scalar loads),
// layer-by-layer kernels, h ping-ponged in d_ws with layout [i][n] (coalesced).
// tanh(z) = 1 - 2*rcp(1 + exp2(C2L*z)),  C2L = 2*log2(e).  2 trans + 5 VALU per element.

#define C2L 2.88539008177792681472f  // 2*log2(e)

__device__ __forceinline__ float fast_tanh_pre(float zc) {
  // zc = 2*log2(e) * z ; returns tanh(z)
  float e = __builtin_amdgcn_exp2f(zc);
  float r = __builtin_amdgcn_rcpf(1.0f + e);
  return fmaf(r, -2.0f, 1.0f);
}

// ---------------- Layer 0: d_in = 2 (inputs x,t) ----------------
// grid (128, 4), block 256.  Each wave: 64 points (lanes), 4 j's.
__global__ __launch_bounds__(256) void kan_layer0(
    const float* __restrict__ x, const float* __restrict__ t,
    const float* __restrict__ W1, const float* __restrict__ B1,   // (64,2,8)
    const float* __restrict__ W2, const float* __restrict__ B2,   // (64,2,8),(64,2)
    float* __restrict__ hout)                                     // [64][8192]
{
  const int tid  = threadIdx.x;
  const int lane = tid & 63;
  const int wave = __builtin_amdgcn_readfirstlane(tid >> 6);
  const int n    = blockIdx.x * 64 + lane;
  const int j0   = blockIdx.y * 16 + wave * 4;
  const float hx = x[n], ht = t[n];
#pragma unroll
  for (int jj = 0; jj < 4; ++jj) {
    const int j = j0 + jj;
    float acc0 = B2[j * 2 + 0];
    float acc1 = B2[j * 2 + 1];
#pragma unroll
    for (int k = 0; k < 8; ++k) {
      float z0 = fmaf(hx, W1[j * 16 + k], B1[j * 16 + k]);
      acc0 = fmaf(W2[j * 16 + k], fast_tanh_pre(z0 * C2L), acc0);
      float z1 = fmaf(ht, W1[j * 16 + 8 + k], B1[j * 16 + 8 + k]);
      acc1 = fmaf(W2[j * 16 + 8 + k], fast_tanh_pre(z1 * C2L), acc1);
    }
    float y = acc0 + acc1;
    hout[j * 8192 + n] = fast_tanh_pre(y * C2L);
  }
}

// ---------------- Layers 1,2: d_in = 64 ----------------
// grid (128, 8), block 256 (4 waves). Wave w handles JT=2 j's: j0 = by*8 + w*2.
// h tile for the block's 64 points staged in LDS as hs[i][lane] (conflict-free).
template <int JT>
__global__ __launch_bounds__(256, 4) void kan_layer64(
    const float* __restrict__ hin,   // [64][8192]
    const float* __restrict__ W1,    // (64,64,8)
    const float* __restrict__ B1,    // (64,64,8)
    const float* __restrict__ W2,    // (64,64,8)
    const float* __restrict__ B2,    // (64,64)
    float* __restrict__ hout)        // [64][8192]
{
  __shared__ float hs[64][64];       // 16 KB
  const int tid  = threadIdx.x;
  const int lane = tid & 63;
  const int wave = __builtin_amdgcn_readfirstlane(tid >> 6);
  const int pg   = blockIdx.x;
  const int n    = pg * 64 + lane;

  // stage h: each wave loads 16 rows, coalesced 256B per row
#pragma unroll
  for (int r = 0; r < 16; ++r) {
    const int i = r * 4 + wave;
    hs[i][lane] = hin[i * 8192 + n];
  }
  __syncthreads();

  const int j0 = blockIdx.y * (4 * JT) + wave * JT;

  float acc[JT][2];
#pragma unroll
  for (int jj = 0; jj < JT; ++jj) { acc[jj][0] = 0.f; acc[jj][1] = 0.f; }

  for (int i = 0; i < 64; ++i) {
    const float hi = hs[i][lane];
#pragma unroll
    for (int jj = 0; jj < JT; ++jj) {
      const int base = (j0 + jj) * 512 + i * 8;   // uniform -> s_load
      const float* __restrict__ w1p = W1 + base;
      const float* __restrict__ b1p = B1 + base;
      const float* __restrict__ w2p = W2 + base;
#pragma unroll
      for (int k = 0; k < 8; ++k) {
        float z = fmaf(hi, w1p[k], b1p[k]);
        float th = fast_tanh_pre(z * C2L);
        acc[jj][k & 1] = fmaf(w2p[k], th, acc[jj][k & 1]);
      }
    }
  }

#pragma unroll
  for (int jj = 0; jj < JT; ++jj) {
    const int j = j0 + jj;
    float b2s = 0.f;
    for (int i = 0; i < 64; ++i) b2s += B2[j * 64 + i];   // uniform -> scalar
    float y = b2s + acc[jj][0] + acc[jj][1];
    hout[j * 8192 + n] = fast_tanh_pre(y * C2L);
  }
}

// ---------------- Output head: u[n] = b + sum_j h[j][n]*Wout[j] ----------------
__global__ __launch_bounds__(256) void kan_out(
    const float* __restrict__ h,      // [64][8192]
    const float* __restrict__ Wout,   // (1,64)
    const float* __restrict__ bout,   // (1,)
    float* __restrict__ u)            // (8192,)
{
  const int n = blockIdx.x * 256 + threadIdx.x;
  float s0 = 0.f, s1 = 0.f, s2 = 0.f, s3 = 0.f;
#pragma unroll
  for (int j = 0; j < 64; j += 4) {
    s0 = fmaf(h[(j + 0) * 8192 + n], Wout[j + 0], s0);
    s1 = fmaf(h[(j + 1) * 8192 + n], Wout[j + 1], s1);
    s2 = fmaf(h[(j + 2) * 8192 + n], Wout[j + 2], s2);
    s3 = fmaf(h[(j + 3) * 8192 + n], Wout[j + 3], s3);
  }
  u[n] = (s0 + s1) + (s2 + s3) + bout[0];
}

extern "C" void kernel_launch(void* const* d_in, const int* in_sizes, int n_in,
                              void* d_out, int out_size, void* d_ws, size_t ws_size,
                              hipStream_t stream) {
  const float* x    = (const float*)d_in[0];
  const float* t    = (const float*)d_in[1];
  const float* W1_0 = (const float*)d_in[2];
  const float* B1_0 = (const float*)d_in[3];
  const float* W2_0 = (const float*)d_in[4];
  const float* B2_0 = (const float*)d_in[5];
  const float* W1_1 = (const float*)d_in[6];
  const float* B1_1 = (const float*)d_in[7];
  const float* W2_1 = (const float*)d_in[8];
  const float* B2_1 = (const float*)d_in[9];
  const float* W1_2 = (const float*)d_in[10];
  const float* B1_2 = (const float*)d_in[11];
  const float* W2_2 = (const float*)d_in[12];
  const float* B2_2 = (const float*)d_in[13];
  const float* Wout = (const float*)d_in[14];
  const float* bout = (const float*)d_in[15];
  float* out = (float*)d_out;

  float* hA = (float*)d_ws;            // [64][8192] = 2 MB
  float* hB = hA + 64 * 8192;          // [64][8192] = 2 MB

  kan_layer0<<<dim3(128, 4), 256, 0, stream>>>(x, t, W1_0, B1_0, W2_0, B2_0, hA);
  kan_layer64<2><<<dim3(128, 8), 256, 0, stream>>>(hA, W1_1, B1_1, W2_1, B2_1, hB);
  kan_layer64<2><<<dim3(128, 8), 256, 0, stream>>>(hB, W1_2, B1_2, W2_2, B2_2, hA);
  kan_out<<<dim3(32), 256, 0, stream>>>(hA, Wout, bout, out);
}

// Round 3
// 227.843 us; speedup vs baseline: 1.0403x; 1.0403x over previous
//
#include <hip/hip_runtime.h>

// KAN-PINN forward, MI355X — round 3.
// Trans-issue-bound (exp2/rcp ~16cyc/wave64 each = 72% of VALU busy).
// Changes vs r2: JT=1 + grid(128,16) -> 8192 waves (100% occ cap);
// inner loop cut to 3 VALU + 2 trans via: h pre-scaled by C2L (folded into
// producer's output fma), B1c = C2L*B1 precomputed, tanh fold
// acc += W2*rcp(1+exp2(zc)); y = S - 2*acc with S = sum(B2)+sum(W2) precomputed.

#define C2L 2.88539008177792681472f  // 2*log2(e)

// ---------------- prep: B1c = C2L*B1 (layers 1,2); S[2][64] ----------------
__global__ __launch_bounds__(256) void kan_prep(
    const float* __restrict__ B1_1, const float* __restrict__ B1_2,
    const float* __restrict__ W2_1, const float* __restrict__ B2_1,
    const float* __restrict__ W2_2, const float* __restrict__ B2_2,
    float* __restrict__ B1c_1, float* __restrict__ B1c_2, float* __restrict__ S)
{
  const int b = blockIdx.x;
  const int t = threadIdx.x;
  if (b < 128) {                       // 128*256 = 32768 elements
    const int idx = b * 256 + t;
    B1c_1[idx] = B1_1[idx] * C2L;
  } else if (b < 256) {
    const int idx = (b - 128) * 256 + t;
    B1c_2[idx] = B1_2[idx] * C2L;
  } else {                             // b == 256: S[j] per layer
    if (t < 128) {
      const int l = t >> 6, j = t & 63;
      const float* __restrict__ W2 = l ? W2_2 : W2_1;
      const float* __restrict__ B2 = l ? B2_2 : B2_1;
      float s = 0.f;
      for (int q = 0; q < 512; ++q) s += W2[j * 512 + q];
      for (int i = 0; i < 64; ++i)  s += B2[j * 64 + i];
      S[t] = s;
    }
  }
}

// ---------------- Layer 0: d_in = 2 ----------------
// grid (128, 4), block 256. Output pre-scaled by C2L for the next layer.
__global__ __launch_bounds__(256) void kan_layer0(
    const float* __restrict__ x, const float* __restrict__ t,
    const float* __restrict__ W1, const float* __restrict__ B1,   // (64,2,8)
    const float* __restrict__ W2, const float* __restrict__ B2,   // (64,2,8),(64,2)
    float* __restrict__ hout)                                     // [64][8192], scaled
{
  const int tid  = threadIdx.x;
  const int lane = tid & 63;
  const int wave = __builtin_amdgcn_readfirstlane(tid >> 6);
  const int n    = blockIdx.x * 64 + lane;
  const int j0   = blockIdx.y * 16 + wave * 4;
  const float hx = x[n], ht = t[n];
#pragma unroll
  for (int jj = 0; jj < 4; ++jj) {
    const int j = j0 + jj;
    float acc0 = B2[j * 2 + 0];
    float acc1 = B2[j * 2 + 1];
#pragma unroll
    for (int k = 0; k < 8; ++k) {
      float z0 = fmaf(hx, W1[j * 16 + k], B1[j * 16 + k]);
      float e0 = __builtin_amdgcn_exp2f(z0 * C2L);
      float r0 = __builtin_amdgcn_rcpf(1.0f + e0);
      acc0 = fmaf(W2[j * 16 + k], fmaf(r0, -2.f, 1.f), acc0);
      float z1 = fmaf(ht, W1[j * 16 + 8 + k], B1[j * 16 + 8 + k]);
      float e1 = __builtin_amdgcn_exp2f(z1 * C2L);
      float r1 = __builtin_amdgcn_rcpf(1.0f + e1);
      acc1 = fmaf(W2[j * 16 + 8 + k], fmaf(r1, -2.f, 1.f), acc1);
    }
    float y = acc0 + acc1;
    float e = __builtin_amdgcn_exp2f(y * C2L);
    float r = __builtin_amdgcn_rcpf(1.0f + e);
    hout[j * 8192 + n] = fmaf(r, -2.f * C2L, C2L);   // C2L * tanh(y)
  }
}

// ---------------- Layers 1,2: d_in = 64 ----------------
// grid (128, 16), block 256 (4 waves, 1 j per wave). 8192 waves total.
// hin is pre-scaled by C2L; inner loop: fma, exp2, add, rcp, fma.
template <int OUT_SCALED>
__global__ __launch_bounds__(256, 8) void kan_layer64(
    const float* __restrict__ hin,   // [64][8192], = C2L * h
    const float* __restrict__ W1,    // (64,64,8)
    const float* __restrict__ B1c,   // (64,64,8) = C2L * B1
    const float* __restrict__ W2,    // (64,64,8)
    const float* __restrict__ S,     // [64]  = sum(B2)+sum(W2) for this layer
    float* __restrict__ hout)        // [64][8192]
{
  __shared__ float hs[64][64];       // 16 KB
  const int tid  = threadIdx.x;
  const int lane = tid & 63;
  const int wave = __builtin_amdgcn_readfirstlane(tid >> 6);
  const int n    = blockIdx.x * 64 + lane;

#pragma unroll
  for (int r = 0; r < 16; ++r) {
    const int i = r * 4 + wave;
    hs[i][lane] = hin[i * 8192 + n];
  }
  __syncthreads();

  const int j = blockIdx.y * 4 + wave;             // uniform per wave
  const float* __restrict__ w1p = W1  + j * 512;
  const float* __restrict__ b1p = B1c + j * 512;
  const float* __restrict__ w2p = W2  + j * 512;

  float acc0 = 0.f, acc1 = 0.f, acc2 = 0.f, acc3 = 0.f;
  for (int i = 0; i < 64; ++i) {
    const float hi = hs[i][lane];
    const int base = i * 8;
#pragma unroll
    for (int k = 0; k < 8; k += 4) {
      float zc0 = fmaf(hi, w1p[base + k + 0], b1p[base + k + 0]);
      float zc1 = fmaf(hi, w1p[base + k + 1], b1p[base + k + 1]);
      float zc2 = fmaf(hi, w1p[base + k + 2], b1p[base + k + 2]);
      float zc3 = fmaf(hi, w1p[base + k + 3], b1p[base + k + 3]);
      float r0 = __builtin_amdgcn_rcpf(1.0f + __builtin_amdgcn_exp2f(zc0));
      float r1 = __builtin_amdgcn_rcpf(1.0f + __builtin_amdgcn_exp2f(zc1));
      float r2 = __builtin_amdgcn_rcpf(1.0f + __builtin_amdgcn_exp2f(zc2));
      float r3 = __builtin_amdgcn_rcpf(1.0f + __builtin_amdgcn_exp2f(zc3));
      acc0 = fmaf(w2p[base + k + 0], r0, acc0);
      acc1 = fmaf(w2p[base + k + 1], r1, acc1);
      acc2 = fmaf(w2p[base + k + 2], r2, acc2);
      acc3 = fmaf(w2p[base + k + 3], r3, acc3);
    }
  }

  const float y = S[j] - 2.f * ((acc0 + acc1) + (acc2 + acc3));
  const float e = __builtin_amdgcn_exp2f(y * C2L);
  const float r = __builtin_amdgcn_rcpf(1.0f + e);
  hout[j * 8192 + n] = OUT_SCALED ? fmaf(r, -2.f * C2L, C2L)   // C2L*tanh(y)
                                  : fmaf(r, -2.f, 1.f);        // tanh(y)
}

// ---------------- Output head ----------------
// grid 128, block 256: block handles 64 points; wave w sums 16 j's; LDS reduce.
__global__ __launch_bounds__(256) void kan_out(
    const float* __restrict__ h,      // [64][8192] (unscaled tanh)
    const float* __restrict__ Wout,   // (1,64)
    const float* __restrict__ bout,   // (1,)
    float* __restrict__ u)            // (8192,)
{
  __shared__ float part[4][64];
  const int lane = threadIdx.x & 63;
  const int wave = __builtin_amdgcn_readfirstlane(threadIdx.x >> 6);
  const int n = blockIdx.x * 64 + lane;
  float s = 0.f;
#pragma unroll
  for (int q = 0; q < 16; ++q) {
    const int j = wave * 16 + q;
    s = fmaf(h[j * 8192 + n], Wout[j], s);
  }
  part[wave][lane] = s;
  __syncthreads();
  if (wave == 0) {
    u[n] = ((part[0][lane] + part[1][lane]) + (part[2][lane] + part[3][lane])) + bout[0];
  }
}

extern "C" void kernel_launch(void* const* d_in, const int* in_sizes, int n_in,
                              void* d_out, int out_size, void* d_ws, size_t ws_size,
                              hipStream_t stream) {
  const float* x    = (const float*)d_in[0];
  const float* t    = (const float*)d_in[1];
  const float* W1_0 = (const float*)d_in[2];
  const float* B1_0 = (const float*)d_in[3];
  const float* W2_0 = (const float*)d_in[4];
  const float* B2_0 = (const float*)d_in[5];
  const float* W1_1 = (const float*)d_in[6];
  const float* B1_1 = (const float*)d_in[7];
  const float* W2_1 = (const float*)d_in[8];
  const float* B2_1 = (const float*)d_in[9];
  const float* W1_2 = (const float*)d_in[10];
  const float* B1_2 = (const float*)d_in[11];
  const float* W2_2 = (const float*)d_in[12];
  const float* B2_2 = (const float*)d_in[13];
  const float* Wout = (const float*)d_in[14];
  const float* bout = (const float*)d_in[15];
  float* out = (float*)d_out;

  float* hA   = (float*)d_ws;          // [64][8192] = 2 MB
  float* hB   = hA + 64 * 8192;        // [64][8192] = 2 MB
  float* B1c1 = hB + 64 * 8192;        // 32768 floats
  float* B1c2 = B1c1 + 32768;          // 32768 floats
  float* Sbuf = B1c2 + 32768;          // 128 floats (S_1 | S_2)

  kan_prep<<<dim3(257), 256, 0, stream>>>(B1_1, B1_2, W2_1, B2_1, W2_2, B2_2,
                                          B1c1, B1c2, Sbuf);
  kan_layer0<<<dim3(128, 4), 256, 0, stream>>>(x, t, W1_0, B1_0, W2_0, B2_0, hA);
  kan_layer64<1><<<dim3(128, 16), 256, 0, stream>>>(hA, W1_1, B1c1, W2_1, Sbuf,      hB);
  kan_layer64<0><<<dim3(128, 16), 256, 0, stream>>>(hB, W1_2, B1c2, W2_2, Sbuf + 64, hA);
  kan_out<<<dim3(128), 256, 0, stream>>>(hA, Wout, bout, out);
}